// Round 3
// baseline (1920.493 us; speedup 1.0000x reference)
//
#include <hip/hip_runtime.h>
#include <math.h>

// Fused Embedder MLP: 4 ->128 ->256 ->128 ->512, exact GELU between layers,
// + emb[token] add, pad rows (all-zero input) -> emb[0].
// Layers 2-4 use mfma_f32_16x16x32_bf16; weights pre-swizzled to B-frag layout
// in d_ws by a prep kernel. Per-wave 32 rows, per-block 128 rows.
//
// R3: R2's (256,4) cap caused scratch spills (FETCH 22->210MB, WRITE 538->919MB,
// VGPR split 64+64 < ~140 live). Fix: two 16-row passes through layers 1-3
// (#pragma unroll 1) so only a2[4]+a3[8] = 48 regs of arrays are live per pass
// (vs 32+64 before); layer 4 stays single-pass sharing fr4 across both halves.
// H2 staging scratch aliases the H3[t=1] LDS region -> 8 KiB/wave, 32 KiB/block.
// Target: <=128 regs, no spill, 4 blocks/CU (16 waves), ~50% occupancy.

typedef float  f32x4  __attribute__((ext_vector_type(4)));
typedef short  s16x8  __attribute__((ext_vector_type(8)));
typedef __bf16 bf16x8 __attribute__((ext_vector_type(8)));

__device__ __forceinline__ unsigned short f2bf(float x) {
  unsigned u = __builtin_bit_cast(unsigned, x);
  u = (u + 0x7FFFu + ((u >> 16) & 1u)) >> 16;   // RNE
  return (unsigned short)u;
}
__device__ __forceinline__ float gelu_exact(float x) {
  return 0.5f * x * (1.0f + erff(x * 0.70710678118654752f));
}
__device__ __forceinline__ void lds_fence() {
  asm volatile("s_waitcnt lgkmcnt(0)" ::: "memory");
  __builtin_amdgcn_sched_barrier(0);
}

// ---------------- prep: W2/W3/W4 fp32 -> bf16 B-fragments in ws ----------------
// Frag f=(nn*KT+kk): element j of lane L is B[kk*32+(L>>4)*8+j][nn*16+(L&15)]
// = W[n][k] (W stored row-major [N_out][K_in]). One 16B store per thread.
__global__ void embed_prep(const float* __restrict__ W2, const float* __restrict__ W3,
                           const float* __restrict__ W4, short* __restrict__ ws) {
  int tid = blockIdx.x * 256 + threadIdx.x;         // 16384 threads total
  const float* W; int K; int base; int e;
  if (tid < 4096)      { W = W2; K = 128; base = 0;     e = tid; }        // 256x128
  else if (tid < 8192) { W = W3; K = 256; base = 32768; e = tid - 4096; } // 128x256
  else                 { W = W4; K = 128; base = 65536; e = tid - 8192; } // 512x128
  int lane = e & 63, f = e >> 6;
  int kt = K >> 5;
  int nn = f / kt, kk = f - nn * kt;
  int n  = nn * 16 + (lane & 15);
  int k0 = kk * 32 + (lane >> 4) * 8;
  const float* src = W + n * K + k0;
  s16x8 v;
#pragma unroll
  for (int j = 0; j < 8; j++) v[j] = (short)f2bf(src[j]);
  *reinterpret_cast<s16x8*>(ws + base + e * 8) = v;
}

// ---------------- main fused kernel ----------------
__global__ __launch_bounds__(256, 4) void embed_main(
    const float* __restrict__ jinfo, const int* __restrict__ jtok,
    const float* __restrict__ emb,   const float* __restrict__ W1,
    const float* __restrict__ b1,    const float* __restrict__ b2,
    const float* __restrict__ b3,    const short* __restrict__ wsW,
    float* __restrict__ out) {
  // 32 KiB: per wave two 16x128 bf16 regions (XOR-swizzled).
  // B0 = H3 rows 0-15. B1 = H2 staging scratch (both passes), then H3 rows 16-31.
  __shared__ short lds_act[4][4096];
  const int lane = threadIdx.x & 63;
  const int wave = threadIdx.x >> 6;
  const int q = lane >> 4, c = lane & 15;
  const int rowBase = blockIdx.x * 128 + wave * 32;
  short* B0 = lds_act[wave];
  short* B1 = lds_act[wave] + 2048;

  const float4* jp = reinterpret_cast<const float4*>(jinfo);
  const s16x8* fr2 = reinterpret_cast<const s16x8*>(wsW);          // 16 nn x 4 kk
  const s16x8* fr3 = reinterpret_cast<const s16x8*>(wsW + 32768);  //  8 nn x 8 kk
  const s16x8* fr4 = reinterpret_cast<const s16x8*>(wsW + 65536);  // 32 nn x 4 kk

  // ======== two passes of 16 rows through layers 1-3 (keep live set small) ====
#pragma unroll 1
  for (int t = 0; t < 2; ++t) {
    // ---- layer 1: [4->128] VALU, emit A-frags (A[m=lane&15][k=q*8+j]) ----
    float4 x = jp[rowBase + t * 16 + c];
    s16x8 a2[4];
#pragma unroll
    for (int kk = 0; kk < 4; kk++) {
#pragma unroll
      for (int j = 0; j < 8; j++) {
        int f = kk * 32 + q * 8 + j;
        float4 w = reinterpret_cast<const float4*>(W1)[f];
        float h = fmaf(w.x, x.x, fmaf(w.y, x.y, fmaf(w.z, x.z, fmaf(w.w, x.w, b1[f]))));
        a2[kk][j] = (short)f2bf(gelu_exact(h));
      }
    }

    // ---- layer 2: [128->256] in two 128-col halves via B1 scratch -> a3 regs --
    s16x8 a3[8];
#pragma unroll
    for (int h = 0; h < 2; h++) {
#pragma unroll
      for (int nn = 0; nn < 8; nn++) {
        int nng = h * 8 + nn;
        f32x4 ac = {0.f, 0.f, 0.f, 0.f};
#pragma unroll
        for (int kk = 0; kk < 4; kk++) {
          bf16x8 bfr = __builtin_bit_cast(bf16x8, fr2[(nng * 4 + kk) * 64 + lane]);
          ac = __builtin_amdgcn_mfma_f32_16x16x32_bf16(__builtin_bit_cast(bf16x8, a2[kk]), bfr, ac, 0, 0, 0);
        }
        int col = nn * 16 + c;                    // local col in [0,128)
        float bias = b2[h * 128 + col];
#pragma unroll
        for (int r = 0; r < 4; r++) {
          int m = q * 4 + r;   // D-layout: row=(lane>>4)*4+r, col=lane&15
          B1[m * 128 + ((((col >> 3) ^ m) & 15) << 3) + (col & 7)] =
              (short)f2bf(gelu_exact(ac[r] + bias));
        }
      }
      lds_fence();
#pragma unroll
      for (int kk = 0; kk < 4; kk++) {
        int m = c;
        int b = kk * 4 + q;            // (k_local>>3), k_local = kk*32+q*8
        a3[h * 4 + kk] = *reinterpret_cast<const s16x8*>(&B1[m * 128 + (((b ^ m) & 15) << 3)]);
      }
      lds_fence();
    }

    // ---- layer 3: [256->128] MFMA, bias+gelu -> H3 region (B0 / B1) ----
    short* Ht = t ? B1 : B0;   // pass 1 overwrites the scratch (last read fenced)
#pragma unroll
    for (int nn = 0; nn < 8; nn++) {
      f32x4 ac = {0.f, 0.f, 0.f, 0.f};
#pragma unroll
      for (int kk = 0; kk < 8; kk++) {
        bf16x8 bfr = __builtin_bit_cast(bf16x8, fr3[(nn * 8 + kk) * 64 + lane]);
        ac = __builtin_amdgcn_mfma_f32_16x16x32_bf16(__builtin_bit_cast(bf16x8, a3[kk]), bfr, ac, 0, 0, 0);
      }
      int col = nn * 16 + c;
      float bias = b3[col];
#pragma unroll
      for (int r = 0; r < 4; r++) {
        int m = q * 4 + r;
        Ht[m * 128 + ((((col >> 3) ^ m) & 15) << 3) + (col & 7)] =
            (short)f2bf(gelu_exact(ac[r] + bias));
      }
    }
    lds_fence();
  }

  // ======== layer 4: [128->512] single pass, fr4 shared across both halves ====
  s16x8 a4s[2][4];
#pragma unroll
  for (int t = 0; t < 2; t++) {
    const short* Ht = t ? B1 : B0;
#pragma unroll
    for (int kk = 0; kk < 4; kk++) {
      int m = c;
      int b = kk * 4 + q;
      a4s[t][kk] = *reinterpret_cast<const s16x8*>(&Ht[m * 128 + (((b ^ m) & 15) << 3)]);
    }
  }

  int   offE[8];
  float mul[8];
#pragma unroll
  for (int i = 0; i < 8; i++) {
    int t = i >> 2, r = i & 3;
    int row = rowBase + t * 16 + q * 4 + r;
    float4 xx = jp[row];
    bool pad = (xx.x == 0.f) && (xx.y == 0.f) && (xx.z == 0.f) && (xx.w == 0.f);
    int tok = jtok[row];
    offE[i] = (pad ? 0 : tok) * 512;
    mul[i]  = pad ? 0.f : 1.f;
  }

#pragma unroll
  for (int nn = 0; nn < 32; nn++) {
    f32x4 ac0 = {0.f, 0.f, 0.f, 0.f}, ac1 = {0.f, 0.f, 0.f, 0.f};
#pragma unroll
    for (int kk = 0; kk < 4; kk++) {
      bf16x8 bfr = __builtin_bit_cast(bf16x8, fr4[(nn * 4 + kk) * 64 + lane]);
      ac0 = __builtin_amdgcn_mfma_f32_16x16x32_bf16(__builtin_bit_cast(bf16x8, a4s[0][kk]), bfr, ac0, 0, 0, 0);
      ac1 = __builtin_amdgcn_mfma_f32_16x16x32_bf16(__builtin_bit_cast(bf16x8, a4s[1][kk]), bfr, ac1, 0, 0, 0);
    }
    int col = nn * 16 + c;
#pragma unroll
    for (int t = 0; t < 2; t++) {
      f32x4 av = t ? ac1 : ac0;
#pragma unroll
      for (int r = 0; r < 4; r++) {
        int i = t * 4 + r;
        int row = rowBase + t * 16 + q * 4 + r;
        out[row * 512 + col] = av[r] * mul[i] + emb[offE[i] + col];
      }
    }
  }
}

extern "C" void kernel_launch(void* const* d_in, const int* in_sizes, int n_in,
                              void* d_out, int out_size, void* d_ws, size_t ws_size,
                              hipStream_t stream) {
  const float* jinfo = (const float*)d_in[0];
  const int*   jtok  = (const int*)d_in[1];
  const float* emb   = (const float*)d_in[2];
  const float* W1    = (const float*)d_in[3];
  const float* b1    = (const float*)d_in[4];
  const float* W2    = (const float*)d_in[5];
  const float* b2    = (const float*)d_in[6];
  const float* W3    = (const float*)d_in[7];
  const float* b3    = (const float*)d_in[8];
  const float* W4    = (const float*)d_in[9];
  float* out = (float*)d_out;
  short* ws  = (short*)d_ws;

  int rows = in_sizes[0] / 4;          // 262144
  embed_prep<<<64, 256, 0, stream>>>(W2, W3, W4, ws);
  embed_main<<<rows / 128, 256, 0, stream>>>(jinfo, jtok, emb, W1, b1, b2, b3, ws, out);
}

// Round 4
// 822.497 us; speedup vs baseline: 2.3350x; 2.3350x over previous
//
#include <hip/hip_runtime.h>
#include <math.h>

// Fused Embedder MLP: 4 ->128 ->256 ->128 ->512, exact GELU between layers,
// + emb[token] add, pad rows (all-zero input) -> emb[0].
// Layers 2-4 use mfma_f32_16x16x32_bf16; weights pre-swizzled to B-frag layout
// in d_ws by a prep kernel. Per-wave 32 rows (2 M-tiles), per-block 128 rows.
//
// History: R0 941us (64K LDS, VGPR 132, 2 blk/CU, no spill).
// R2: 32K LDS + (256,4) cap -> allocator split 64 arch/64 acc -> scratch spill
//     (FETCH 210MB, WRITE 919MB), 533us. R3: two-pass restructure under same
//     cap -> 2.7GB spill, 1499us. Conclusion: 128-reg cap is infeasible for
//     this kernel; the arch half of the forced 64/64 split is the binding
//     constraint, not total array bytes.
// R4: R2 structure verbatim, cap relaxed to __launch_bounds__(256,3):
//     budget ~170 regs (arch ~106 + acc 64) > true live set (~132 per R0).
//     3 blocks/CU (VGPR-bound; LDS 32K would allow 5), zero spill expected.

typedef float  f32x4  __attribute__((ext_vector_type(4)));
typedef short  s16x8  __attribute__((ext_vector_type(8)));
typedef __bf16 bf16x8 __attribute__((ext_vector_type(8)));

__device__ __forceinline__ unsigned short f2bf(float x) {
  unsigned u = __builtin_bit_cast(unsigned, x);
  u = (u + 0x7FFFu + ((u >> 16) & 1u)) >> 16;   // RNE
  return (unsigned short)u;
}
__device__ __forceinline__ float gelu_exact(float x) {
  return 0.5f * x * (1.0f + erff(x * 0.70710678118654752f));
}
__device__ __forceinline__ void lds_fence() {
  asm volatile("s_waitcnt lgkmcnt(0)" ::: "memory");
  __builtin_amdgcn_sched_barrier(0);
}

// ---------------- prep: W2/W3/W4 fp32 -> bf16 B-fragments in ws ----------------
// Frag f=(nn*KT+kk): element j of lane L is B[kk*32+(L>>4)*8+j][nn*16+(L&15)]
// = W[n][k] (W stored row-major [N_out][K_in]). One 16B store per thread.
__global__ void embed_prep(const float* __restrict__ W2, const float* __restrict__ W3,
                           const float* __restrict__ W4, short* __restrict__ ws) {
  int tid = blockIdx.x * 256 + threadIdx.x;         // 16384 threads total
  const float* W; int K; int base; int e;
  if (tid < 4096)      { W = W2; K = 128; base = 0;     e = tid; }        // 256x128
  else if (tid < 8192) { W = W3; K = 256; base = 32768; e = tid - 4096; } // 128x256
  else                 { W = W4; K = 128; base = 65536; e = tid - 8192; } // 512x128
  int lane = e & 63, f = e >> 6;
  int kt = K >> 5;
  int nn = f / kt, kk = f - nn * kt;
  int n  = nn * 16 + (lane & 15);
  int k0 = kk * 32 + (lane >> 4) * 8;
  const float* src = W + n * K + k0;
  s16x8 v;
#pragma unroll
  for (int j = 0; j < 8; j++) v[j] = (short)f2bf(src[j]);
  *reinterpret_cast<s16x8*>(ws + base + e * 8) = v;
}

// ---------------- main fused kernel ----------------
__global__ __launch_bounds__(256, 3) void embed_main(
    const float* __restrict__ jinfo, const int* __restrict__ jtok,
    const float* __restrict__ emb,   const float* __restrict__ W1,
    const float* __restrict__ b1,    const float* __restrict__ b2,
    const float* __restrict__ b3,    const short* __restrict__ wsW,
    float* __restrict__ out) {
  // 32 KiB: per-wave 32x128 bf16 staging, XOR-swizzled. Reused 3x:
  // H2 half 0 -> H2 half 1 -> H3.
  __shared__ short lds_act[4][4096];
  const int lane = threadIdx.x & 63;
  const int wave = threadIdx.x >> 6;
  const int q = lane >> 4, c = lane & 15;
  const int rowBase = blockIdx.x * 128 + wave * 32;
  short* S = lds_act[wave];

  const float4* jp = reinterpret_cast<const float4*>(jinfo);

  // ---- layer 1: [4->128] VALU, emit A-frags (A[m=lane&15][k=q*8+j]) ----
  float4 x0 = jp[rowBase + c];
  float4 x1 = jp[rowBase + 16 + c];
  s16x8 a2s[2][4];
#pragma unroll
  for (int kk = 0; kk < 4; kk++) {
#pragma unroll
    for (int j = 0; j < 8; j++) {
      int f = kk * 32 + q * 8 + j;
      float4 w = reinterpret_cast<const float4*>(W1)[f];
      float bb = b1[f];
      float h0 = fmaf(w.x, x0.x, fmaf(w.y, x0.y, fmaf(w.z, x0.z, fmaf(w.w, x0.w, bb))));
      float h1 = fmaf(w.x, x1.x, fmaf(w.y, x1.y, fmaf(w.z, x1.z, fmaf(w.w, x1.w, bb))));
      a2s[0][kk][j] = (short)f2bf(gelu_exact(h0));
      a2s[1][kk][j] = (short)f2bf(gelu_exact(h1));
    }
  }

  const s16x8* fr2 = reinterpret_cast<const s16x8*>(wsW);          // 16 nn x 4 kk
  const s16x8* fr3 = reinterpret_cast<const s16x8*>(wsW + 32768);  //  8 nn x 8 kk
  const s16x8* fr4 = reinterpret_cast<const s16x8*>(wsW + 65536);  // 32 nn x 4 kk

  // ---- layer 2: [128->256] MFMA in two 128-col halves; each half is staged
  // to the 8 KiB/wave buffer and immediately pulled into a3s registers. ----
  s16x8 a3s[2][8];
#pragma unroll
  for (int h = 0; h < 2; h++) {
#pragma unroll
    for (int nn = 0; nn < 8; nn++) {
      int nng = h * 8 + nn;
      f32x4 ac0 = {0.f, 0.f, 0.f, 0.f}, ac1 = {0.f, 0.f, 0.f, 0.f};
#pragma unroll
      for (int kk = 0; kk < 4; kk++) {
        bf16x8 bfr = __builtin_bit_cast(bf16x8, fr2[(nng * 4 + kk) * 64 + lane]);
        ac0 = __builtin_amdgcn_mfma_f32_16x16x32_bf16(__builtin_bit_cast(bf16x8, a2s[0][kk]), bfr, ac0, 0, 0, 0);
        ac1 = __builtin_amdgcn_mfma_f32_16x16x32_bf16(__builtin_bit_cast(bf16x8, a2s[1][kk]), bfr, ac1, 0, 0, 0);
      }
      int col = nn * 16 + c;                    // local col in [0,128)
      float bias = b2[h * 128 + col];
#pragma unroll
      for (int t = 0; t < 2; t++) {
        f32x4 av = t ? ac1 : ac0;
#pragma unroll
        for (int r = 0; r < 4; r++) {
          int m = t * 16 + q * 4 + r;   // D-layout: row=(lane>>4)*4+r, col=lane&15
          S[m * 128 + ((((col >> 3) ^ m) & 15) << 3) + (col & 7)] =
              (short)f2bf(gelu_exact(av[r] + bias));
        }
      }
    }
    // per-wave fence: writes above complete before reads below (DS in-order
    // per wave; "memory" clobber + sched_barrier stop compiler reordering)
    lds_fence();
#pragma unroll
    for (int t = 0; t < 2; t++) {
#pragma unroll
      for (int kk = 0; kk < 4; kk++) {
        int m = t * 16 + c;
        int b = kk * 4 + q;            // (k_local>>3), k_local = kk*32+q*8
        a3s[t][h * 4 + kk] = *reinterpret_cast<const s16x8*>(&S[m * 128 + (((b ^ m) & 15) << 3)]);
      }
    }
    lds_fence();
  }

  // ---- layer 3: [256->128] MFMA, bias+gelu, stage H3 (reuses S) ----
#pragma unroll
  for (int nn = 0; nn < 8; nn++) {
    f32x4 ac0 = {0.f, 0.f, 0.f, 0.f}, ac1 = {0.f, 0.f, 0.f, 0.f};
#pragma unroll
    for (int kk = 0; kk < 8; kk++) {
      bf16x8 bfr = __builtin_bit_cast(bf16x8, fr3[(nn * 8 + kk) * 64 + lane]);
      ac0 = __builtin_amdgcn_mfma_f32_16x16x32_bf16(__builtin_bit_cast(bf16x8, a3s[0][kk]), bfr, ac0, 0, 0, 0);
      ac1 = __builtin_amdgcn_mfma_f32_16x16x32_bf16(__builtin_bit_cast(bf16x8, a3s[1][kk]), bfr, ac1, 0, 0, 0);
    }
    int col = nn * 16 + c;
    float bias = b3[col];
#pragma unroll
    for (int t = 0; t < 2; t++) {
      f32x4 av = t ? ac1 : ac0;
#pragma unroll
      for (int r = 0; r < 4; r++) {
        int m = t * 16 + q * 4 + r;
        S[m * 128 + ((((col >> 3) ^ m) & 15) << 3) + (col & 7)] =
            (short)f2bf(gelu_exact(av[r] + bias));
      }
    }
  }
  lds_fence();

  // ---- layer 4: [128->512] MFMA, + emb[token] / pad->emb[0], store ----
  s16x8 a4s[2][4];
#pragma unroll
  for (int t = 0; t < 2; t++) {
#pragma unroll
    for (int kk = 0; kk < 4; kk++) {
      int m = t * 16 + c;
      int b = kk * 4 + q;
      a4s[t][kk] = *reinterpret_cast<const s16x8*>(&S[m * 128 + (((b ^ m) & 15) << 3)]);
    }
  }

  int   offE[8];
  float mul[8];
#pragma unroll
  for (int i = 0; i < 8; i++) {
    int t = i >> 2, r = i & 3;
    int row = rowBase + t * 16 + q * 4 + r;
    float4 x = jp[row];
    bool pad = (x.x == 0.f) && (x.y == 0.f) && (x.z == 0.f) && (x.w == 0.f);
    int tok = jtok[row];
    offE[i] = (pad ? 0 : tok) * 512;
    mul[i]  = pad ? 0.f : 1.f;
  }

#pragma unroll
  for (int nn = 0; nn < 32; nn++) {
    f32x4 ac0 = {0.f, 0.f, 0.f, 0.f}, ac1 = {0.f, 0.f, 0.f, 0.f};
#pragma unroll
    for (int kk = 0; kk < 4; kk++) {
      bf16x8 bfr = __builtin_bit_cast(bf16x8, fr4[(nn * 4 + kk) * 64 + lane]);
      ac0 = __builtin_amdgcn_mfma_f32_16x16x32_bf16(__builtin_bit_cast(bf16x8, a4s[0][kk]), bfr, ac0, 0, 0, 0);
      ac1 = __builtin_amdgcn_mfma_f32_16x16x32_bf16(__builtin_bit_cast(bf16x8, a4s[1][kk]), bfr, ac1, 0, 0, 0);
    }
    int col = nn * 16 + c;
#pragma unroll
    for (int t = 0; t < 2; t++) {
      f32x4 av = t ? ac1 : ac0;
#pragma unroll
      for (int r = 0; r < 4; r++) {
        int i = t * 4 + r;
        int row = rowBase + t * 16 + q * 4 + r;
        out[row * 512 + col] = av[r] * mul[i] + emb[offE[i] + col];
      }
    }
  }
}

extern "C" void kernel_launch(void* const* d_in, const int* in_sizes, int n_in,
                              void* d_out, int out_size, void* d_ws, size_t ws_size,
                              hipStream_t stream) {
  const float* jinfo = (const float*)d_in[0];
  const int*   jtok  = (const int*)d_in[1];
  const float* emb   = (const float*)d_in[2];
  const float* W1    = (const float*)d_in[3];
  const float* b1    = (const float*)d_in[4];
  const float* W2    = (const float*)d_in[5];
  const float* b2    = (const float*)d_in[6];
  const float* W3    = (const float*)d_in[7];
  const float* b3    = (const float*)d_in[8];
  const float* W4    = (const float*)d_in[9];
  float* out = (float*)d_out;
  short* ws  = (short*)d_ws;

  int rows = in_sizes[0] / 4;          // 262144
  embed_prep<<<64, 256, 0, stream>>>(W2, W3, W4, ws);
  embed_main<<<rows / 128, 256, 0, stream>>>(jinfo, jtok, emb, W1, b1, b2, b3, ws, out);
}